// Round 1
// baseline (119.371 us; speedup 1.0000x reference)
//
#include <hip/hip_runtime.h>
#include <hip/hip_bf16.h>

// ---------------------------------------------------------------------------
// BatchedGraphSAGE: h = BN(relu(l2norm(cat[x@Wx^T+bx, m1@Wn^T+bn, m2.., m3..])))
// Key trick: mean(gather(x)) @ W^T == mean(gather(x @ W^T))  (mean is linear),
// so we project once (1.07 GF instead of 2.15 GF + raw-feature gathers) and
// gather/average the 2MB bf16 projected tensor, which is fully L2-resident.
// ---------------------------------------------------------------------------

typedef short  s16x8 __attribute__((ext_vector_type(8)));   // 8 bf16 (MFMA frag)
typedef float  f32x4 __attribute__((ext_vector_type(4)));
typedef unsigned short u16x4 __attribute__((ext_vector_type(4)));

#define NREP 16          // replicated atomic buffers for BN partial sums
#define P3_ROWS 4        // (b,n) rows per block in k2

// ws layout (bytes); total ~25.6 MB
#define OFF_XBF    (0u)                    // x_bf   [4096][256] bf16 : 2 MB
#define OFF_WCAT   (2097152u)              // Wcat   [512][256]  bf16 : 0.25 MB
#define OFF_XWX    (2359296u)              // xWx    [4096][256] f32  : 4 MB
#define OFF_XWN    (6553600u)              // xWn    [4096][256] bf16 : 2 MB
#define OFF_HBUF   (8650752u)              // h      [4096][1024] f32 : 16 MB
#define OFF_SUMS   (25427968u)             // sums   [16][2048]  f32  : 128 KB
#define OFF_COEFA  (25559040u)             // A coef [1024] f32
#define OFF_COEFB  (25563136u)             // B coef [1024] f32

__device__ __forceinline__ unsigned short f2bf(float f) {
    unsigned int u = __float_as_uint(f);
    u = (u + 0x7FFFu + ((u >> 16) & 1u)) >> 16;          // RNE
    return (unsigned short)u;
}
__device__ __forceinline__ float bf2f(unsigned short h) {
    return __uint_as_float(((unsigned int)h) << 16);
}

// k0: convert x (1048576 f32) and [Wx;Wn] (131072 f32) to bf16
__global__ __launch_bounds__(256) void k0_convert(
    const float* __restrict__ x, const float* __restrict__ Wx,
    const float* __restrict__ Wn,
    unsigned short* __restrict__ x_bf, unsigned short* __restrict__ Wcat)
{
    int e = (blockIdx.x * 256 + threadIdx.x) * 4;
    if (e < 1048576) {
        float4 v = *(const float4*)&x[e];
        u16x4 o; o[0]=f2bf(v.x); o[1]=f2bf(v.y); o[2]=f2bf(v.z); o[3]=f2bf(v.w);
        *(u16x4*)&x_bf[e] = o;
    } else {
        int e2 = e - 1048576;
        if (e2 < 131072) {
            const float* src = (e2 < 65536) ? &Wx[e2] : &Wn[e2 - 65536];
            float4 v = *(const float4*)src;
            u16x4 o; o[0]=f2bf(v.x); o[1]=f2bf(v.y); o[2]=f2bf(v.z); o[3]=f2bf(v.w);
            *(u16x4*)&Wcat[e2] = o;
        }
    }
}

// k1: OUT[4096][512] = x_bf @ Wcat^T. Cols 0..255 -> xWx (f32), 256..511 -> xWn (bf16).
// 16x16x32 bf16 MFMA; block = 4 waves, tile 64(M)x64(N); frags straight from L2.
__global__ __launch_bounds__(256) void k1_gemm(
    const unsigned short* __restrict__ A, const unsigned short* __restrict__ W,
    float* __restrict__ xWx, unsigned short* __restrict__ xWn)
{
    const int tid = threadIdx.x;
    const int w = tid >> 6, l = tid & 63;
    const int l15 = l & 15, lhi = l >> 4;
    const int rowBase = blockIdx.x * 64 + w * 16;
    const int colBase = blockIdx.y * 64;

    f32x4 acc[4] = {};
    const unsigned short* ap = &A[(rowBase + l15) * 256 + lhi * 8];
    const unsigned short* wp = &W[(colBase + l15) * 256 + lhi * 8];
    #pragma unroll
    for (int k0 = 0; k0 < 256; k0 += 32) {
        s16x8 a = *(const s16x8*)(ap + k0);
        #pragma unroll
        for (int c = 0; c < 4; ++c) {
            s16x8 b = *(const s16x8*)(wp + c * 16 * 256 + k0);
            acc[c] = __builtin_amdgcn_mfma_f32_16x16x32_bf16(a, b, acc[c], 0, 0, 0);
        }
    }
    // C/D layout (verified m89): col = lane&15, row = (lane>>4)*4 + reg
    const int row0 = rowBase + lhi * 4;
    if (colBase < 256) {
        #pragma unroll
        for (int c = 0; c < 4; ++c)
            #pragma unroll
            for (int r = 0; r < 4; ++r)
                xWx[(row0 + r) * 256 + colBase + c * 16 + l15] = acc[c][r];
    } else {
        #pragma unroll
        for (int c = 0; c < 4; ++c)
            #pragma unroll
            for (int r = 0; r < 4; ++r)
                xWn[(row0 + r) * 256 + (colBase - 256) + c * 16 + l15] = f2bf(acc[c][r]);
    }
}

// k2: per (b,n) row: 3 gather-means over xWn, + biases, L2-normalize over 1024,
// relu, write h, accumulate BN partial sums (replicated atomics).
__global__ __launch_bounds__(256) void k2_rows(
    const float* __restrict__ xWx, const unsigned short* __restrict__ xWn,
    const int* __restrict__ idx1, const int* __restrict__ idx2,
    const int* __restrict__ idx3,
    const float* __restrict__ bx, const float* __restrict__ bn,
    float* __restrict__ hbuf, float* __restrict__ sums)
{
    __shared__ int lidx[96];
    __shared__ float red[4];
    const int t = threadIdx.x;
    const float bxv = bx[t], bnv = bn[t];
    float sA0=0,sA1=0,sA2=0,sA3=0, sQ0=0,sQ1=0,sQ2=0,sQ3=0;

    for (int rr = 0; rr < P3_ROWS; ++rr) {
        const int r = blockIdx.x * P3_ROWS + rr;
        const int b = r >> 9, n = r & 511;
        __syncthreads();                       // protect lidx/red reuse
        if (t < 96) {
            int s = t >> 5, k = t & 31;
            const int* ip = (s == 0) ? idx1 : ((s == 1) ? idx2 : idx3);
            lidx[t] = ip[n * 32 + k];
        }
        __syncthreads();
        const unsigned short* base = &xWn[(unsigned)b * (512u * 256u) + (unsigned)t];
        float m1 = 0.f, m2 = 0.f, m3 = 0.f;
        #pragma unroll
        for (int k = 0; k < 32; ++k) m1 += bf2f(base[lidx[k] * 256]);
        #pragma unroll
        for (int k = 0; k < 32; ++k) m2 += bf2f(base[lidx[32 + k] * 256]);
        #pragma unroll
        for (int k = 0; k < 32; ++k) m3 += bf2f(base[lidx[64 + k] * 256]);

        float hs = xWx[r * 256 + t] + bxv;
        float h1 = m1 * (1.f / 32.f) + bnv;
        float h2 = m2 * (1.f / 32.f) + bnv;
        float h3 = m3 * (1.f / 32.f) + bnv;

        float p = hs*hs + h1*h1 + h2*h2 + h3*h3;
        #pragma unroll
        for (int off = 32; off > 0; off >>= 1) p += __shfl_down(p, off);
        if ((t & 63) == 0) red[t >> 6] = p;
        __syncthreads();
        float total = red[0] + red[1] + red[2] + red[3];
        float invn = 1.0f / fmaxf(sqrtf(total), 1e-12f);

        hs = fmaxf(hs * invn, 0.f); h1 = fmaxf(h1 * invn, 0.f);
        h2 = fmaxf(h2 * invn, 0.f); h3 = fmaxf(h3 * invn, 0.f);

        float* hr = &hbuf[(unsigned)r * 1024u];
        hr[t] = hs; hr[256 + t] = h1; hr[512 + t] = h2; hr[768 + t] = h3;

        sA0 += hs; sQ0 += hs*hs;  sA1 += h1; sQ1 += h1*h1;
        sA2 += h2; sQ2 += h2*h2;  sA3 += h3; sQ3 += h3*h3;
    }
    float* sb = &sums[(blockIdx.x & (NREP - 1)) * 2048];
    atomicAdd(&sb[         t], sA0); atomicAdd(&sb[1024 +          t], sQ0);
    atomicAdd(&sb[ 256 +   t], sA1); atomicAdd(&sb[1024 +  256 +   t], sQ1);
    atomicAdd(&sb[ 512 +   t], sA2); atomicAdd(&sb[1024 +  512 +   t], sQ2);
    atomicAdd(&sb[ 768 +   t], sA3); atomicAdd(&sb[1024 +  768 +   t], sQ3);
}

// k3: fold NREP partial buffers -> per-channel BN affine coefs
__global__ __launch_bounds__(256) void k3_coef(
    const float* __restrict__ sums, const float* __restrict__ gamma,
    const float* __restrict__ beta, float* __restrict__ cA, float* __restrict__ cB)
{
    int c = blockIdx.x * 256 + threadIdx.x;   // 4 blocks -> 1024 channels
    float s = 0.f, s2 = 0.f;
    #pragma unroll
    for (int rep = 0; rep < NREP; ++rep) {
        s  += sums[rep * 2048 + c];
        s2 += sums[rep * 2048 + 1024 + c];
    }
    float mu  = s  * (1.f / 4096.f);
    float var = s2 * (1.f / 4096.f) - mu * mu;
    float a = gamma[c] / sqrtf(var + 1e-5f);
    cA[c] = a;
    cB[c] = beta[c] - mu * a;
}

// k4: out = h * A[c] + B[c], float4-vectorized streaming pass
__global__ __launch_bounds__(256) void k4_apply(
    const float* __restrict__ hbuf, const float* __restrict__ cA,
    const float* __restrict__ cB, float* __restrict__ out)
{
    int gid = blockIdx.x * 256 + threadIdx.x;
    int c0 = (gid & 255) * 4;                 // (gid*4) mod 1024
    float4 h = *(const float4*)&hbuf[(unsigned)gid * 4u];
    float4 a = *(const float4*)&cA[c0];
    float4 b = *(const float4*)&cB[c0];
    float4 o;
    o.x = h.x * a.x + b.x;  o.y = h.y * a.y + b.y;
    o.z = h.z * a.z + b.z;  o.w = h.w * a.w + b.w;
    *(float4*)&out[(unsigned)gid * 4u] = o;
}

extern "C" void kernel_launch(void* const* d_in, const int* in_sizes, int n_in,
                              void* d_out, int out_size, void* d_ws, size_t ws_size,
                              hipStream_t stream)
{
    const float* x     = (const float*)d_in[0];
    const int*   idx1  = (const int*)  d_in[1];
    const int*   idx2  = (const int*)  d_in[2];
    const int*   idx3  = (const int*)  d_in[3];
    const float* Wx    = (const float*)d_in[4];
    const float* bx    = (const float*)d_in[5];
    const float* Wn    = (const float*)d_in[6];
    const float* bn    = (const float*)d_in[7];
    const float* gamma = (const float*)d_in[8];
    const float* beta  = (const float*)d_in[9];

    char* ws = (char*)d_ws;
    unsigned short* x_bf = (unsigned short*)(ws + OFF_XBF);
    unsigned short* Wcat = (unsigned short*)(ws + OFF_WCAT);
    float*          xWx  = (float*)         (ws + OFF_XWX);
    unsigned short* xWn  = (unsigned short*)(ws + OFF_XWN);
    float*          hbuf = (float*)         (ws + OFF_HBUF);
    float*          sums = (float*)         (ws + OFF_SUMS);
    float*          cA   = (float*)         (ws + OFF_COEFA);
    float*          cB   = (float*)         (ws + OFF_COEFB);

    k0_convert<<<1152, 256, 0, stream>>>(x, Wx, Wn, x_bf, Wcat);
    k1_gemm<<<dim3(64, 8), 256, 0, stream>>>(x_bf, Wcat, xWx, xWn);
    hipMemsetAsync(sums, 0, NREP * 2048 * sizeof(float), stream);
    k2_rows<<<1024, 256, 0, stream>>>(xWx, xWn, idx1, idx2, idx3, bx, bn, hbuf, sums);
    k3_coef<<<4, 256, 0, stream>>>(sums, gamma, beta, cA, cB);
    k4_apply<<<4096, 256, 0, stream>>>(hbuf, cA, cB, (float*)d_out);
}